// Round 1
// baseline (674.293 us; speedup 1.0000x reference)
//
#include <hip/hip_runtime.h>
#include <stdint.h>

#define N_FEAT 136
#define COL_DOCLEN 14
#define COL_WHOLE_LEN 16
#define COL_TF 24
#define COL_INLINK 127
#define COL_OUTLINK 128
#define COL_PAGERANK 129

// ---------------- Threefry-2x32 (JAX-compatible, 20 rounds) ----------------
__device__ __forceinline__ void threefry2x32(uint32_t k0, uint32_t k1,
                                             uint32_t& x0, uint32_t& x1) {
  const uint32_t ks0 = k0, ks1 = k1, ks2 = k0 ^ k1 ^ 0x1BD11BDAu;
  x0 += ks0; x1 += ks1;
#define TF_ROUND(r) { x0 += x1; x1 = (x1 << (r)) | (x1 >> (32 - (r))); x1 ^= x0; }
  TF_ROUND(13) TF_ROUND(15) TF_ROUND(26) TF_ROUND(6)
  x0 += ks1; x1 += ks2 + 1u;
  TF_ROUND(17) TF_ROUND(29) TF_ROUND(16) TF_ROUND(24)
  x0 += ks2; x1 += ks0 + 2u;
  TF_ROUND(13) TF_ROUND(15) TF_ROUND(26) TF_ROUND(6)
  x0 += ks0; x1 += ks1 + 3u;
  TF_ROUND(17) TF_ROUND(29) TF_ROUND(16) TF_ROUND(24)
  x0 += ks1; x1 += ks2 + 4u;
  TF_ROUND(13) TF_ROUND(15) TF_ROUND(26) TF_ROUND(6)
  x0 += ks2; x1 += ks0 + 5u;
#undef TF_ROUND
}

__device__ __forceinline__ float tf_noise(uint32_t i) {
  uint32_t x0 = 0u, x1 = i;
  threefry2x32(0u, 1u, x0, x1);
  const uint32_t bits = x0 ^ x1;
  return __uint_as_float((bits >> 9) | 0x3f800000u) - 1.0f;
}

// ---------------- K1: stream all docs once ----------------
// Per doc: write tf, dl, link-combo; accumulate sum of col 16.
// Sequential-by-row access -> near-streaming HBM pattern (vs random gather).
__global__ void doc_pass_kernel(const float* __restrict__ gf,
                                const float* __restrict__ p_prw,
                                const float* __restrict__ p_inw,
                                const float* __restrict__ p_outw,
                                float* __restrict__ tf_a,
                                float* __restrict__ dl_a,
                                float* __restrict__ link_a,
                                float* __restrict__ sum,
                                int n_docs) {
  const int j = blockIdx.x * blockDim.x + threadIdx.x;
  float wl = 0.f;
  if (j < n_docs) {
    const size_t base = (size_t)j * N_FEAT;
    const float dl  = gf[base + COL_DOCLEN];
    wl              = gf[base + COL_WHOLE_LEN];
    const float tf  = gf[base + COL_TF];
    const float inl = gf[base + COL_INLINK];
    // cols 128,129 are 8B-aligned (base even) -> one float2: (outlink, pagerank)
    const float2 op = *reinterpret_cast<const float2*>(gf + base + COL_OUTLINK);
    tf_a[j]   = tf;
    dl_a[j]   = dl;
    link_a[j] = p_prw[0] * op.y + p_inw[0] * inl + p_outw[0] * op.x;
  }
  // wave-64 reduce of col-16 values
  for (int off = 32; off > 0; off >>= 1) wl += __shfl_down(wl, off, 64);
  __shared__ float ws_[4];
  const int lane = threadIdx.x & 63, wave = threadIdx.x >> 6;
  if (lane == 0) ws_[wave] = wl;
  __syncthreads();
  if (threadIdx.x == 0) atomicAdd(sum, ws_[0] + ws_[1] + ws_[2] + ws_[3]);
}

// ---------------- K2: per-doc final score base (needs avg_doc_len) ----------------
__global__ void doc_score_kernel(const float* __restrict__ tf_a,
                                 const float* __restrict__ dl_a,
                                 const float* __restrict__ link_a,
                                 const float* __restrict__ p_k1,
                                 const float* __restrict__ p_b,
                                 const float* __restrict__ p_bm25w,
                                 const float* __restrict__ col_sum,
                                 float* __restrict__ s_doc,
                                 int n_docs, float total_docs) {
  const int j = blockIdx.x * blockDim.x + threadIdx.x;
  if (j >= n_docs) return;
  const float k1 = p_k1[0];
  const float b  = p_b[0];
  const float bm25w = p_bm25w[0];
  const float avg_doc_len = col_sum[0] / total_docs;
  const float idf = logf(0.5f / (total_docs + 0.5f) + 1.0f);
  const float tf = tf_a[j];
  const float dl = dl_a[j];
  const float numer = tf * (k1 + 1.0f);
  const float denom = tf + k1 * (1.0f - b + b * (dl / avg_doc_len));
  const float bm25 = idf * (numer / denom);
  s_doc[j] = bm25w * bm25 + link_a[j];
}

// ---------------- K3: 4B gather from L2-resident s_doc + noise ----------------
__global__ void gather_kernel(const int* __restrict__ idx,
                              const float* __restrict__ s_doc,
                              const float* __restrict__ p_fresh,
                              float* __restrict__ out, int batch) {
  const int t = blockIdx.x * blockDim.x + threadIdx.x;
  int i = t * 4;
  const float fresh = p_fresh[0];
  if (i + 3 < batch) {
    const int4 id = *reinterpret_cast<const int4*>(idx + i);
    float4 r;
    r.x = s_doc[id.x] + tf_noise((uint32_t)(i + 0)) * fresh;
    r.y = s_doc[id.y] + tf_noise((uint32_t)(i + 1)) * fresh;
    r.z = s_doc[id.z] + tf_noise((uint32_t)(i + 2)) * fresh;
    r.w = s_doc[id.w] + tf_noise((uint32_t)(i + 3)) * fresh;
    *reinterpret_cast<float4*>(out + i) = r;
  } else {
    for (; i < batch; ++i)
      out[i] = s_doc[idx[i]] + tf_noise((uint32_t)i) * fresh;
  }
}

// ---------------- Fallback (old path) if workspace too small ----------------
__global__ void col16_sum_kernel(const float* __restrict__ gf, float* __restrict__ sum,
                                 int n_docs) {
  int stride = gridDim.x * blockDim.x;
  float v = 0.f;
  for (int j = blockIdx.x * blockDim.x + threadIdx.x; j < n_docs; j += stride)
    v += gf[(size_t)j * N_FEAT + COL_WHOLE_LEN];
  for (int off = 32; off > 0; off >>= 1) v += __shfl_down(v, off, 64);
  __shared__ float ws[4];
  int lane = threadIdx.x & 63, wave = threadIdx.x >> 6;
  if (lane == 0) ws[wave] = v;
  __syncthreads();
  if (threadIdx.x == 0) {
    float t = 0.f;
    int nw = blockDim.x >> 6;
    for (int w = 0; w < nw; ++w) t += ws[w];
    atomicAdd(sum, t);
  }
}

__global__ void score_kernel(const int* __restrict__ idx,
                             const float* __restrict__ gf,
                             const float* __restrict__ p_k1,
                             const float* __restrict__ p_b,
                             const float* __restrict__ p_bm25w,
                             const float* __restrict__ p_prw,
                             const float* __restrict__ p_inw,
                             const float* __restrict__ p_outw,
                             const float* __restrict__ p_fresh,
                             const float* __restrict__ col_sum,
                             float* __restrict__ out,
                             int batch, float total_docs) {
  int i = blockIdx.x * blockDim.x + threadIdx.x;
  if (i >= batch) return;
  const float k1 = p_k1[0];
  const float b  = p_b[0];
  const float bm25w = p_bm25w[0];
  const float avg_doc_len = col_sum[0] / total_docs;
  const float idf = logf(0.5f / (total_docs + 0.5f) + 1.0f);
  const size_t base = (size_t)idx[i] * N_FEAT;
  const float tf   = gf[base + COL_TF];
  const float dl   = gf[base + COL_DOCLEN];
  const float pr   = gf[base + COL_PAGERANK];
  const float inl  = gf[base + COL_INLINK];
  const float outl = gf[base + COL_OUTLINK];
  const float numer = tf * (k1 + 1.0f);
  const float denom = tf + k1 * (1.0f - b + b * (dl / avg_doc_len));
  const float bm25 = idf * (numer / denom);
  out[i] = bm25w * bm25 + p_prw[0] * pr + p_inw[0] * inl + p_outw[0] * outl
         + tf_noise((uint32_t)i) * p_fresh[0];
}

extern "C" void kernel_launch(void* const* d_in, const int* in_sizes, int n_in,
                              void* d_out, int out_size, void* d_ws, size_t ws_size,
                              hipStream_t stream) {
  const int*   batch_indices = (const int*)d_in[0];
  const float* gf            = (const float*)d_in[1];
  const float* k1    = (const float*)d_in[2];
  const float* b     = (const float*)d_in[3];
  const float* bm25w = (const float*)d_in[4];
  const float* prw   = (const float*)d_in[5];
  const float* inw   = (const float*)d_in[6];
  const float* outw  = (const float*)d_in[7];
  const float* fresh = (const float*)d_in[8];
  float* out = (float*)d_out;

  const int batch  = in_sizes[0];
  const int n_docs = in_sizes[1] / N_FEAT;

  float* ws      = (float*)d_ws;
  float* col_sum = ws;                 // 1 float (+ padding to 64)
  float* tf_a    = ws + 64;
  float* dl_a    = tf_a + n_docs;
  float* link_a  = dl_a + n_docs;
  float* s_doc   = link_a + n_docs;
  const size_t need = (64 + 4 * (size_t)n_docs) * sizeof(float);

  hipMemsetAsync(col_sum, 0, sizeof(float), stream);

  const int tpb = 256;
  if (ws_size >= need) {
    const int b_doc = (n_docs + tpb - 1) / tpb;
    doc_pass_kernel<<<b_doc, tpb, 0, stream>>>(gf, prw, inw, outw,
                                               tf_a, dl_a, link_a, col_sum, n_docs);
    doc_score_kernel<<<b_doc, tpb, 0, stream>>>(tf_a, dl_a, link_a, k1, b, bm25w,
                                                col_sum, s_doc, n_docs, (float)n_docs);
    const int b_gat = ((batch + 3) / 4 + tpb - 1) / tpb;
    gather_kernel<<<b_gat, tpb, 0, stream>>>(batch_indices, s_doc, fresh, out, batch);
  } else {
    col16_sum_kernel<<<1024, tpb, 0, stream>>>(gf, col_sum, n_docs);
    const int blocks = (batch + tpb - 1) / tpb;
    score_kernel<<<blocks, tpb, 0, stream>>>(
        batch_indices, gf, k1, b, bm25w, prw, inw, outw, fresh,
        col_sum, out, batch, (float)n_docs);
  }
}